// Round 20
// baseline (576.835 us; speedup 1.0000x reference)
//
#include <hip/hip_runtime.h>
#include <hip/hip_bf16.h>

// ---------------------------------------------------------------------------
// ReformerBlockPreLN on MI355X — round 20: r19 + attention T14 async-stage
// (prefetch next chunk's K/V into regs; gather hides under compute) and
// T13 defer-max (skip O-rescale when max growth <= 8; exact for LSE).
// B=2 S=4096 D=1024 H=16 DH=64 R=2 NBUCK=64 CHUNK=128 MLP=4096
// ---------------------------------------------------------------------------

typedef short short8 __attribute__((ext_vector_type(8)));
typedef float f32x4 __attribute__((ext_vector_type(4)));
typedef unsigned short us4 __attribute__((ext_vector_type(4)));

__device__ __forceinline__ unsigned short f2bf(float f) {
  unsigned u = __builtin_bit_cast(unsigned, f);
  u += 0x7FFFu + ((u >> 16) & 1u);
  return (unsigned short)(u >> 16);
}

__device__ __forceinline__ float bf2f(unsigned short u) {
  return __builtin_bit_cast(float, ((unsigned)u) << 16);
}

// gelu tanh-form as sigmoid: 0.5x(1+tanh(u)) == x * sigma(2u)
__device__ __forceinline__ float gelu_f(float x) {
  float y = 1.5957691216057308f * (x + 0.044715f * x * x * x);
  return x / (1.f + __expf(-y));
}

__device__ __forceinline__ void load_lds16(const void* g, void* l) {
  __builtin_amdgcn_global_load_lds(
      (const __attribute__((address_space(1))) unsigned int*)g,
      (__attribute__((address_space(3))) unsigned int*)l, 16, 0, 0);
}

// ---------------------------------------------------------------------------
// transpose + cast fp32 [R][C] -> bf16 [C][R]
// ---------------------------------------------------------------------------
__global__ __launch_bounds__(256) void transpose_cast(
    const float* __restrict__ in, unsigned short* __restrict__ out, int R,
    int C) {
  __shared__ float tile[32][33];
  int ctiles = C >> 5;
  int bx = blockIdx.x % ctiles;
  int by = blockIdx.x / ctiles;
  int tx = threadIdx.x & 31;
  int ty = threadIdx.x >> 5;
#pragma unroll
  for (int i = 0; i < 32; i += 8)
    tile[ty + i][tx] = in[(size_t)(by * 32 + ty + i) * C + bx * 32 + tx];
  __syncthreads();
#pragma unroll
  for (int i = 0; i < 32; i += 8)
    out[(size_t)(bx * 32 + ty + i) * R + by * 32 + tx] = f2bf(tile[tx][ty + i]);
}

// ---------------------------------------------------------------------------
// LayerNorm over D=1024, fp32 in -> bf16 out. One block per row.
// ---------------------------------------------------------------------------
__global__ __launch_bounds__(256) void ln_bf16(const float* __restrict__ x,
                                               const float* __restrict__ sc,
                                               const float* __restrict__ bi,
                                               unsigned short* __restrict__ y) {
  int row = blockIdx.x, tid = threadIdx.x, lane = tid & 63, wv = tid >> 6;
  const float* xr = x + (size_t)row * 1024;
  float4 v = *(const float4*)(xr + tid * 4);
  float s1 = v.x + v.y + v.z + v.w;
  float s2 = v.x * v.x + v.y * v.y + v.z * v.z + v.w * v.w;
#pragma unroll
  for (int o = 1; o < 64; o <<= 1) {
    s1 += __shfl_xor(s1, o);
    s2 += __shfl_xor(s2, o);
  }
  __shared__ float a1[4], a2[4];
  if (lane == 0) {
    a1[wv] = s1;
    a2[wv] = s2;
  }
  __syncthreads();
  s1 = a1[0] + a1[1] + a1[2] + a1[3];
  s2 = a2[0] + a2[1] + a2[2] + a2[3];
  float mu = s1 * (1.f / 1024.f);
  float var = s2 * (1.f / 1024.f) - mu * mu;
  float rs = rsqrtf(var + 1e-6f);
  int c = tid * 4;
  us4 o4;
  o4.x = f2bf((v.x - mu) * rs * sc[c + 0] + bi[c + 0]);
  o4.y = f2bf((v.y - mu) * rs * sc[c + 1] + bi[c + 1]);
  o4.z = f2bf((v.z - mu) * rs * sc[c + 2] + bi[c + 2]);
  o4.w = f2bf((v.w - mu) * rs * sc[c + 3] + bi[c + 3]);
  *(us4*)(y + (size_t)row * 1024 + c) = o4;
}

// ---------------------------------------------------------------------------
// LayerNorm over D=1024, bf16 in -> bf16 out. One block per row.
// ---------------------------------------------------------------------------
__global__ __launch_bounds__(256) void ln_bf16_b(
    const unsigned short* __restrict__ x, const float* __restrict__ sc,
    const float* __restrict__ bi, unsigned short* __restrict__ y) {
  int row = blockIdx.x, tid = threadIdx.x, lane = tid & 63, wv = tid >> 6;
  const unsigned short* xr = x + (size_t)row * 1024;
  us4 vb = *(const us4*)(xr + tid * 4);
  float v0 = bf2f(vb.x), v1 = bf2f(vb.y), v2 = bf2f(vb.z), v3 = bf2f(vb.w);
  float s1 = v0 + v1 + v2 + v3;
  float s2 = v0 * v0 + v1 * v1 + v2 * v2 + v3 * v3;
#pragma unroll
  for (int o = 1; o < 64; o <<= 1) {
    s1 += __shfl_xor(s1, o);
    s2 += __shfl_xor(s2, o);
  }
  __shared__ float a1[4], a2[4];
  if (lane == 0) {
    a1[wv] = s1;
    a2[wv] = s2;
  }
  __syncthreads();
  s1 = a1[0] + a1[1] + a1[2] + a1[3];
  s2 = a2[0] + a2[1] + a2[2] + a2[3];
  float mu = s1 * (1.f / 1024.f);
  float var = s2 * (1.f / 1024.f) - mu * mu;
  float rs = rsqrtf(var + 1e-6f);
  int c = tid * 4;
  us4 o4;
  o4.x = f2bf((v0 - mu) * rs * sc[c + 0] + bi[c + 0]);
  o4.y = f2bf((v1 - mu) * rs * sc[c + 1] + bi[c + 1]);
  o4.z = f2bf((v2 - mu) * rs * sc[c + 2] + bi[c + 2]);
  o4.w = f2bf((v3 - mu) * rs * sc[c + 3] + bi[c + 3]);
  *(us4*)(y + (size_t)row * 1024 + c) = o4;
}

#define PRE_MFMA()                                   \
  __builtin_amdgcn_sched_barrier(0);                 \
  __builtin_amdgcn_s_barrier();                      \
  asm volatile("s_waitcnt lgkmcnt(0)" ::: "memory"); \
  __builtin_amdgcn_sched_barrier(0);                 \
  __builtin_amdgcn_s_setprio(1)
#define POST_MFMA()                  \
  __builtin_amdgcn_s_setprio(0);     \
  __builtin_amdgcn_sched_barrier(0); \
  __builtin_amdgcn_s_barrier()

// ---------------------------------------------------------------------------
// 8-phase 256² 8-wave GEMM (m201 template, r12-proven). BM=BN=256, BK=64,
// 512 threads, 2x4 waves, counted vmcnt(6).
// EPI 1: bias+gelu -> bf16. EPI 5: fused qkv split store (q scaled 0.125).
// ---------------------------------------------------------------------------
template <int EPI>
__global__ __launch_bounds__(512, 2) void gemm_8p(
    const unsigned short* __restrict__ A, const unsigned short* __restrict__ Bt,
    const float* __restrict__ bias, unsigned short* __restrict__ Cb,
    unsigned short* __restrict__ Cb2, int M, int N, int K) {
  __shared__ unsigned short sA[2][256 * 64];
  __shared__ unsigned short sB[2][256 * 64];
  const int nbx = N >> 8;
  const int nwg = gridDim.x;
  const int cpx = nwg >> 3;
  const int bid = blockIdx.x;
  const int swz = (bid & 7) * cpx + (bid >> 3);
  const int bx = swz % nbx;
  const int by = swz / nbx;
  const int tid = threadIdx.x;
  const int lane = tid & 63;
  const int wid = tid >> 6;
  const int wr = wid >> 2;
  const int wc = wid & 3;
  const int l15 = lane & 15;
  const int lhi = lane >> 4;

  const int sr = tid >> 3;  // 0..63
  const int sgl = (tid & 7) ^ (sr & 7);
  const unsigned short* Ab = A + ((size_t)(by * 256) + sr) * K + sgl * 8;
  const unsigned short* Bb = Bt + ((size_t)(bx * 256) + sr) * K + sgl * 8;

  f32x4 acc[8][4];
#pragma unroll
  for (int m = 0; m < 8; ++m)
#pragma unroll
    for (int n = 0; n < 4; ++n) {
      f32x4 z = {0.f, 0.f, 0.f, 0.f};
      acc[m][n] = z;
    }

  const int KT = K >> 6;

  auto ISSUE = [&](int mat, int half, int kt, int buf) {
    const unsigned short* src =
        (mat ? Bb : Ab) + (size_t)(half * 128) * K + kt * 64;
    char* d =
        (char*)(mat ? &sB[buf][0] : &sA[buf][0]) + half * 16384 + tid * 16;
    load_lds16(src, d);
    load_lds16(src + (size_t)64 * K, d + 8192);
  };

  auto rdA = [&](int m, int ks, int c) {
    int row = ((m & 4) << 5) + wr * 64 + ((m & 3) << 4) + l15;
    int pg = ((ks << 2) + lhi) ^ (l15 & 7);
    return *(const short8*)&sA[c][row * 64 + pg * 8];
  };
  auto rdB = [&](int n, int ks, int c) {
    int row = ((n & 2) << 6) + wc * 32 + ((n & 1) << 4) + l15;
    int pg = ((ks << 2) + lhi) ^ (l15 & 7);
    return *(const short8*)&sB[c][row * 64 + pg * 8];
  };

  // prologue
  ISSUE(0, 0, 0, 0);
  ISSUE(1, 0, 0, 0);
  ISSUE(0, 1, 0, 0);
  ISSUE(1, 1, 0, 0);
  asm volatile("s_waitcnt vmcnt(4)" ::: "memory");
  if (KT > 1) {
    ISSUE(0, 0, 1, 1);
    ISSUE(1, 0, 1, 1);
    ISSUE(0, 1, 1, 1);
  }
  asm volatile("s_waitcnt vmcnt(6)" ::: "memory");
  __builtin_amdgcn_sched_barrier(0);
  __builtin_amdgcn_s_barrier();

  for (int kt = 0; kt < KT; ++kt) {
    const int c = kt & 1;
    short8 a0[4][2], a1[4][2], b0[2][2], b1[2][2];

    // phase 0: (m0-3, n0-1); issue Bh1(kt+1) -> buf c^1
#pragma unroll
    for (int m = 0; m < 4; ++m)
#pragma unroll
      for (int ks = 0; ks < 2; ++ks) a0[m][ks] = rdA(m, ks, c);
#pragma unroll
    for (int n = 0; n < 2; ++n)
#pragma unroll
      for (int ks = 0; ks < 2; ++ks) b0[n][ks] = rdB(n, ks, c);
    if (kt + 1 < KT) ISSUE(1, 1, kt + 1, c ^ 1);
    PRE_MFMA();
#pragma unroll
    for (int m = 0; m < 4; ++m)
#pragma unroll
      for (int n = 0; n < 2; ++n)
#pragma unroll
        for (int ks = 0; ks < 2; ++ks)
          acc[m][n] = __builtin_amdgcn_mfma_f32_16x16x32_bf16(
              a0[m][ks], b0[n][ks], acc[m][n], 0, 0, 0);
    POST_MFMA();

    // phase 1: (m4-7, n0-1); issue Ah0(kt+2) -> buf c
#pragma unroll
    for (int m = 0; m < 4; ++m)
#pragma unroll
      for (int ks = 0; ks < 2; ++ks) a1[m][ks] = rdA(4 + m, ks, c);
    if (kt + 2 < KT) ISSUE(0, 0, kt + 2, c);
    PRE_MFMA();
#pragma unroll
    for (int m = 0; m < 4; ++m)
#pragma unroll
      for (int n = 0; n < 2; ++n)
#pragma unroll
        for (int ks = 0; ks < 2; ++ks)
          acc[4 + m][n] = __builtin_amdgcn_mfma_f32_16x16x32_bf16(
              a1[m][ks], b0[n][ks], acc[4 + m][n], 0, 0, 0);
    POST_MFMA();

    // phase 2: (m4-7, n2-3); issue Bh0(kt+2) -> buf c
#pragma unroll
    for (int n = 0; n < 2; ++n)
#pragma unroll
      for (int ks = 0; ks < 2; ++ks) b1[n][ks] = rdB(2 + n, ks, c);
    if (kt + 2 < KT) ISSUE(1, 0, kt + 2, c);
    PRE_MFMA();
#pragma unroll
    for (int m = 0; m < 4; ++m)
#pragma unroll
      for (int n = 0; n < 2; ++n)
#pragma unroll
        for (int ks = 0; ks < 2; ++ks)
          acc[4 + m][2 + n] = __builtin_amdgcn_mfma_f32_16x16x32_bf16(
              a1[m][ks], b1[n][ks], acc[4 + m][2 + n], 0, 0, 0);
    POST_MFMA();

    // phase 3: (m0-3, n2-3), no reads; issue Ah1(kt+2) -> buf c
    if (kt + 2 < KT) ISSUE(0, 1, kt + 2, c);
    __builtin_amdgcn_s_setprio(1);
#pragma unroll
    for (int m = 0; m < 4; ++m)
#pragma unroll
      for (int n = 0; n < 2; ++n)
#pragma unroll
        for (int ks = 0; ks < 2; ++ks)
          acc[m][2 + n] = __builtin_amdgcn_mfma_f32_16x16x32_bf16(
              a0[m][ks], b1[n][ks], acc[m][2 + n], 0, 0, 0);
    __builtin_amdgcn_s_setprio(0);
    if (kt + 1 < KT) {
      if (kt + 2 < KT) {
        asm volatile("s_waitcnt vmcnt(6)" ::: "memory");
      } else {
        asm volatile("s_waitcnt vmcnt(0)" ::: "memory");
      }
      __builtin_amdgcn_sched_barrier(0);
      __builtin_amdgcn_s_barrier();
    }
  }

  const int r0 = by * 256 + wr * 64;
  const int c0 = bx * 256 + wc * 32;
#pragma unroll
  for (int m = 0; m < 8; ++m) {
    const int rb = r0 + ((m & 4) << 5) + ((m & 3) << 4) + lhi * 4;
#pragma unroll
    for (int n = 0; n < 4; ++n) {
      const int cc = c0 + ((n & 2) << 6) + ((n & 1) << 4) + l15;
#pragma unroll
      for (int i = 0; i < 4; ++i) {
        const int rr = rb + i;
        float vacc = acc[m][n][i];
        if (EPI == 1) {
          Cb[(size_t)rr * N + cc] = f2bf(gelu_f(vacc + bias[cc]));
        } else if (EPI == 5) {
          if (cc < 1024) {
            // q pre-scaled by 1/sqrt(DH)=0.125 (exact exponent shift)
            Cb[(size_t)rr * 1024 + cc] = f2bf(vacc * 0.125f);
          } else {
            Cb2[(size_t)rr * 1024 + (cc - 1024)] = f2bf(vacc);
          }
        }
      }
    }
  }
}

#undef PRE_MFMA
#undef POST_MFMA

// ---------------------------------------------------------------------------
// 2-phase bf16 GEMM (r12-proven), 128x128 tile, BK=64, grid 512 = 2
// blocks/CU. Used for wout, mlp2.
// EPI 3: acc + fp32 res -> bf16 (wout -> x2b).
// EPI 4: acc + bias + bf16 res -> fp32 (mlp2 -> d_out).
// ---------------------------------------------------------------------------
template <int EPI>
__global__ __launch_bounds__(256) void gemm_bt(
    const unsigned short* __restrict__ A, const unsigned short* __restrict__ Bt,
    const float* __restrict__ bias, const float* __restrict__ res,
    const unsigned short* __restrict__ resb, float* __restrict__ Cf,
    unsigned short* __restrict__ Cb, int M, int N, int K) {
  __shared__ unsigned short sA[2][128 * 64];
  __shared__ unsigned short sB[2][128 * 64];
  const int nbx = N / 128;
  const int nwg = gridDim.x;
  const int cpx = nwg >> 3;
  const int bid = blockIdx.x;
  const int swz = (bid & 7) * cpx + (bid >> 3);
  const int bx = swz % nbx;
  const int by = swz / nbx;
  const int tid = threadIdx.x;
  const int lane = tid & 63;
  const int wave = tid >> 6;
  const int wr = wave >> 1, wc = wave & 1;
  const int l15 = lane & 15;
  const int lhi = lane >> 4;

  const int srow = tid >> 3;  // 0..31
  const int sgl = (tid & 7) ^ (srow & 7);
  const unsigned short* Ag = A + (size_t)(by * 128 + srow) * K + sgl * 8;
  const unsigned short* Bg = Bt + (size_t)(bx * 128 + srow) * K + sgl * 8;

  f32x4 acc[4][4];
#pragma unroll
  for (int m = 0; m < 4; ++m)
#pragma unroll
    for (int n = 0; n < 4; ++n) {
      f32x4 z = {0.f, 0.f, 0.f, 0.f};
      acc[m][n] = z;
    }

  const int KT = K / 64;

  auto STAGE = [&](int ktile, int buf) {
    const unsigned short* As = Ag + (size_t)ktile * 64;
    const unsigned short* Bs = Bg + (size_t)ktile * 64;
#pragma unroll
    for (int i = 0; i < 4; ++i) {
      load_lds16(As + (size_t)i * 32 * K,
                 (char*)&sA[buf][0] + tid * 16 + i * 4096);
      load_lds16(Bs + (size_t)i * 32 * K,
                 (char*)&sB[buf][0] + tid * 16 + i * 4096);
    }
  };

  STAGE(0, 0);
  __syncthreads();

  int cur = 0;
  const int arow = wr * 64 + l15;
  const int brow = wc * 64 + l15;

  for (int kt = 0; kt < KT; ++kt) {
    if (kt + 1 < KT) STAGE(kt + 1, cur ^ 1);
#pragma unroll
    for (int ks = 0; ks < 2; ++ks) {
      const int koff = (((ks * 4 + lhi) ^ (l15 & 7)) << 3);
      short8 af[4], bfv[4];
#pragma unroll
      for (int m = 0; m < 4; ++m)
        af[m] = *(const short8*)&sA[cur][(arow + m * 16) * 64 + koff];
#pragma unroll
      for (int n = 0; n < 4; ++n)
        bfv[n] = *(const short8*)&sB[cur][(brow + n * 16) * 64 + koff];
#pragma unroll
      for (int m = 0; m < 4; ++m)
#pragma unroll
        for (int n = 0; n < 4; ++n)
          acc[m][n] = __builtin_amdgcn_mfma_f32_16x16x32_bf16(
              af[m], bfv[n], acc[m][n], 0, 0, 0);
    }
    __syncthreads();
    cur ^= 1;
  }

  const int r0 = by * 128 + wr * 64;
  const int c0 = bx * 128 + wc * 64;
#pragma unroll
  for (int m = 0; m < 4; ++m) {
#pragma unroll
    for (int n = 0; n < 4; ++n) {
#pragma unroll
      for (int i = 0; i < 4; ++i) {
        int rr = r0 + m * 16 + lhi * 4 + i;
        int cc = c0 + n * 16 + l15;
        float vacc = acc[m][n][i];
        if (EPI == 3) {
          float t = vacc + res[(size_t)rr * N + cc];
          Cb[(size_t)rr * N + cc] = f2bf(t);
        } else if (EPI == 4) {
          float t = vacc + bias[cc] + bf2f(resb[(size_t)rr * N + cc]);
          Cf[(size_t)rr * N + cc] = t;
        }
      }
    }
  }
}

// ---------------------------------------------------------------------------
// Buckets + normalized-K pack. One wave per (b,h,s) token. bf16 qk input
// (pre-scaled by 0.125 — cancels in normalization; eps shift negligible).
// ---------------------------------------------------------------------------
__global__ __launch_bounds__(256) void bucket_kernel(
    const unsigned short* __restrict__ qk, const float* __restrict__ rot,
    unsigned short* __restrict__ knb, int* __restrict__ buckets) {
  __shared__ float rotl[64 * 64];
  __shared__ float xnl[4][64];
  int tid = threadIdx.x, lane = tid & 63, wv = tid >> 6;
  for (int i = tid; i < 4096; i += 256) rotl[i] = rot[i];
  __syncthreads();
  for (int it = 0; it < 8; ++it) {
    int g = (it * 4096 + blockIdx.x) * 4 + wv;
    int bh = g >> 12;
    int s = g & 4095;
    int b = bh >> 4, h = bh & 15;
    size_t rowoff = (size_t)(b * 4096 + s) * 1024 + h * 64;
    float x = bf2f(qk[rowoff + lane]);
    float ss = x * x;
#pragma unroll
    for (int o = 1; o < 64; o <<= 1) ss += __shfl_xor(ss, o);
    float rn = 1.f / (sqrtf(ss) + 1e-6f);
    float xn = x * rn;
    knb[rowoff + lane] = f2bf(xn);
    xnl[wv][lane] = xn;
    __syncthreads();
    int r_ = lane >> 5, m_ = lane & 31;
    float a = 0.f;
#pragma unroll 16
    for (int d = 0; d < 64; ++d) a += xnl[wv][d] * rotl[d * 64 + r_ * 32 + m_];
    float bv;
    int bi;
    if (a >= 0.f) {
      bv = a;
      bi = m_;
    } else {
      bv = -a;
      bi = m_ + 32;
    }
#pragma unroll
    for (int o = 16; o >= 1; o >>= 1) {
      float ov = __shfl_xor(bv, o);
      int oi = __shfl_xor(bi, o);
      if (ov > bv || (ov == bv && oi < bi)) {
        bv = ov;
        bi = oi;
      }
    }
    if (m_ == 0) buckets[((size_t)bh * 2 + r_) * 4096 + s] = bi;
    __syncthreads();
  }
}

// ---------------------------------------------------------------------------
// Parallel stable counting sort. One block (256 threads) per (b,h,r).
// ---------------------------------------------------------------------------
#define HSTR 65

__global__ __launch_bounds__(256) void sort_kernel(
    const int* __restrict__ buckets, int* __restrict__ order) {
  __shared__ unsigned int hist[256 * HSTR];
  __shared__ unsigned int bucketStart[64];
  const int bhr = blockIdx.x;
  const int t = threadIdx.x;
  const int* bk = buckets + (size_t)bhr * 4096;

  unsigned int* hrow = &hist[t * HSTR];
#pragma unroll
  for (int b = 0; b < 64; ++b) hrow[b] = 0u;

  int bks[16];
  {
    const int4* bp = (const int4*)(bk + t * 16);
#pragma unroll
    for (int j4 = 0; j4 < 4; ++j4) {
      int4 v = bp[j4];
      bks[j4 * 4 + 0] = v.x;
      bks[j4 * 4 + 1] = v.y;
      bks[j4 * 4 + 2] = v.z;
      bks[j4 * 4 + 3] = v.w;
    }
  }
#pragma unroll
  for (int j = 0; j < 16; ++j) hrow[bks[j]]++;
  __syncthreads();

  if (t < 64) {
    unsigned int acc = 0;
    for (int t2 = 0; t2 < 256; ++t2) {
      unsigned int c = hist[t2 * HSTR + t];
      hist[t2 * HSTR + t] = acc;
      acc += c;
    }
    bucketStart[t] = acc;
  }
  __syncthreads();
  if (t == 0) {
    unsigned int acc = 0;
    for (int b = 0; b < 64; ++b) {
      unsigned int c = bucketStart[b];
      bucketStart[b] = acc;
      acc += c;
    }
  }
  __syncthreads();

  int* op = order + (size_t)bhr * 4096;
#pragma unroll
  for (int j = 0; j < 16; ++j) {
    int b = bks[j];
    unsigned int pos = bucketStart[b] + hrow[b];
    hrow[b]++;
    op[pos] = t * 16 + j;
  }
}

// ---------------------------------------------------------------------------
// MFMA LSH attention: all-bf16, granule-XOR-swizzled LDS, T14 async-stage
// (next chunk's K/V prefetched to regs, gather hides under compute), T13
// defer-max (skip rescale when max growth <= 8 — exact for logsumexp).
// q pre-scaled by 0.125 so dval = sacc directly.
// ---------------------------------------------------------------------------
__global__ __launch_bounds__(256, 2) void lsh_attn_mfma(
    const unsigned short* __restrict__ qb, const unsigned short* __restrict__ knb,
    const unsigned short* __restrict__ vb, const int* __restrict__ order,
    unsigned short* __restrict__ ob, float* __restrict__ slog) {
  __shared__ unsigned short Kls[128 * 64];
  __shared__ unsigned short Vt[64 * 128];
  __shared__ unsigned short Pls[4][32 * 128];
  __shared__ int qtokL[128];
  __shared__ int btok[128];

  const int bid = blockIdx.x;                   // grid = 2048
  const int swz = (bid & 7) * 256 + (bid >> 3); // chunked XCD swizzle
  const int c = swz & 31;
  const int bhr = swz >> 5;
  const int bh = bhr >> 1;
  const int h = bh & 15, b = bh >> 4;
  const int* ord = order + (size_t)bhr * 4096;
  const int tid = threadIdx.x, lane = tid & 63, wv = tid >> 6;
  const int l15 = lane & 15, lhi = lane >> 4;

  if (tid < 128) qtokL[tid] = ord[c * 128 + tid];
  __syncthreads();

  short8 qf[2][2];
#pragma unroll
  for (int mt = 0; mt < 2; ++mt) {
#pragma unroll
    for (int ks = 0; ks < 2; ++ks) {
      int tok = qtokL[wv * 32 + mt * 16 + l15];
      qf[mt][ks] = *(const short8*)(qb + (size_t)(b * 4096 + tok) * 1024 +
                                    h * 64 + ks * 32 + lhi * 8);
    }
  }

  // T14: prefetch chunk 0's K/V rows into registers
  const int row = tid >> 1, half = tid & 1;
  const int r7 = row & 7;
  const int gt = row >> 3;
  int ktok_r = ord[c * 128 + row];
  short8 kreg[4], vreg[4];
  {
    size_t rowoff = (size_t)(b * 4096 + ktok_r) * 1024 + h * 64 + half * 32;
    const short8* kp = (const short8*)(knb + rowoff);
    const short8* vp = (const short8*)(vb + rowoff);
#pragma unroll
    for (int i = 0; i < 4; ++i) {
      kreg[i] = kp[i];
      vreg[i] = vp[i];
    }
  }

  float mrun[2][4], lrun[2][4];
  f32x4 oacc[2][4];
#pragma unroll
  for (int mt = 0; mt < 2; ++mt)
#pragma unroll
    for (int i = 0; i < 4; ++i) {
      mrun[mt][i] = -1e30f;
      lrun[mt][i] = 0.f;
    }
#pragma unroll
  for (int mt = 0; mt < 2; ++mt)
#pragma unroll
    for (int n = 0; n < 4; ++n) {
      f32x4 z = {0.f, 0.f, 0.f, 0.f};
      oacc[mt][n] = z;
    }

  for (int st = 0; st < 3; ++st) {
    __syncthreads();  // previous chunk's LDS reads complete
    // write registered K/V into LDS (data already resident — no mem wait)
    if (half == 0) btok[row] = ktok_r;
#pragma unroll
    for (int i = 0; i < 4; ++i)
      *(short8*)&Kls[row * 64 + (((half << 2) + i) ^ r7) * 8] = kreg[i];
#pragma unroll
    for (int i = 0; i < 4; ++i) {
      short8 vw = vreg[i];
      int d0 = half * 32 + i * 8;
#pragma unroll
      for (int j = 0; j < 8; ++j)
        Vt[(d0 + j) * 128 + ((gt ^ j) << 3) + r7] = (unsigned short)vw[j];
    }
    // issue next chunk's gathers — latency hides under QK/softmax/PV below
    if (st < 2) {
      int kcn = (st == 0) ? ((c + 31) & 31) : ((c + 1) & 31);
      ktok_r = ord[kcn * 128 + row];
      size_t rowoff = (size_t)(b * 4096 + ktok_r) * 1024 + h * 64 + half * 32;
      const short8* kp = (const short8*)(knb + rowoff);
      const short8* vp = (const short8*)(vb + rowoff);
#pragma unroll
      for (int i = 0; i < 4; ++i) {
        kreg[i] = kp[i];
        vreg[i] = vp[i];
      }
    }
    __syncthreads();  // staged K/V visible

    f32x4 sacc[2][8];
#pragma unroll
    for (int mt = 0; mt < 2; ++mt)
#pragma unroll
      for (int n = 0; n < 8; ++n) {
        f32x4 z = {0.f, 0.f, 0.f, 0.f};
        sacc[mt][n] = z;
      }
#pragma unroll
    for (int ks = 0; ks < 2; ++ks) {
      short8 kf[8];
#pragma unroll
      for (int n = 0; n < 8; ++n)
        kf[n] = *(const short8*)&Kls[(n * 16 + l15) * 64 +
                                     ((((ks << 2) + lhi) ^ (l15 & 7)) << 3)];
#pragma unroll
      for (int mt = 0; mt < 2; ++mt)
#pragma unroll
        for (int n = 0; n < 8; ++n)
          sacc[mt][n] = __builtin_amdgcn_mfma_f32_16x16x32_bf16(
              qf[mt][ks], kf[n], sacc[mt][n], 0, 0, 0);
    }

    int ktA[8];
#pragma unroll
    for (int n = 0; n < 8; ++n) ktA[n] = btok[n * 16 + l15];
#pragma unroll
    for (int mt = 0; mt < 2; ++mt) {
#pragma unroll
      for (int i = 0; i < 4; ++i) {
        int rL = mt * 16 + lhi * 4 + i;
        int qt = qtokL[wv * 32 + rL];
        float sv[8];
        float mx = -1e30f;
#pragma unroll
        for (int n = 0; n < 8; ++n) {
          float s = sacc[mt][n][i];
          if (ktA[n] == qt) s -= 1e5f;
          sv[n] = s;
          mx = fmaxf(mx, s);
        }
#pragma unroll
        for (int d = 1; d < 16; d <<= 1) mx = fmaxf(mx, __shfl_xor(mx, d));
        // T13 defer-max: only rescale when the max grew by > 8.
        float mold = mrun[mt][i];
        if (mx > mold + 8.0f) {
          float scl = __expf(mold - mx);
          lrun[mt][i] *= scl;
#pragma unroll
          for (int n = 0; n < 4; ++n) oacc[mt][n][i] *= scl;
          mrun[mt][i] = mx;
          mold = mx;
        }
        float ps = 0.f;
        const int rx = rL & 7;
#pragma unroll
        for (int n = 0; n < 8; ++n) {
          float p = __expf(sv[n] - mold);
          ps += p;
          int gp = (n << 1) + (l15 >> 3);
          Pls[wv][rL * 128 + ((gp ^ rx) << 3) + (l15 & 7)] = f2bf(p);
        }
#pragma unroll
        for (int d = 1; d < 16; d <<= 1) ps += __shfl_xor(ps, d);
        lrun[mt][i] += ps;
      }
    }

#pragma unroll
    for (int ks = 0; ks < 4; ++ks) {
      const int pg = (((ks << 2) + lhi) ^ (l15 & 7)) << 3;
      short8 pf[2];
#pragma unroll
      for (int mt = 0; mt < 2; ++mt)
        pf[mt] = *(const short8*)&Pls[wv][(mt * 16 + l15) * 128 + pg];
      short8 vfr[4];
#pragma unroll
      for (int n = 0; n < 4; ++n)
        vfr[n] = *(const short8*)&Vt[(n * 16 + l15) * 128 + pg];
#pragma unroll
      for (int mt = 0; mt < 2; ++mt)
#pragma unroll
        for (int n = 0; n < 4; ++n)
          oacc[mt][n] = __builtin_amdgcn_mfma_f32_16x16x32_bf16(
              pf[mt], vfr[n], oacc[mt][n], 0, 0, 0);
    }
  }

#pragma unroll
  for (int mt = 0; mt < 2; ++mt) {
#pragma unroll
    for (int i = 0; i < 4; ++i) {
      int qrow = wv * 32 + mt * 16 + lhi * 4 + i;
      int tok = qtokL[qrow];
      float l = lrun[mt][i];
      float invl = 1.f / l;
      if (l15 == 0) slog[(size_t)bhr * 4096 + tok] = logf(l) + mrun[mt][i];
      unsigned short* orow = ob + ((size_t)bhr * 4096 + tok) * 64;
#pragma unroll
      for (int n = 0; n < 4; ++n)
        orow[n * 16 + l15] = f2bf(oacc[mt][n][i] * invl);
    }
  }
}

// ---------------------------------------------------------------------------
// Combine hash rounds: w = softmax over r of slog; att = sum_r w_r * o_r.
// ---------------------------------------------------------------------------
__global__ __launch_bounds__(256) void combine_rounds(
    const unsigned short* __restrict__ ob, const float* __restrict__ slog,
    unsigned short* __restrict__ att) {
  int g = blockIdx.x * 4 + (threadIdx.x >> 6);
  int lane = threadIdx.x & 63;
  int h = g & 15;
  int bs = g >> 4;
  int b = bs >> 12;
  int s = bs & 4095;
  size_t base = ((size_t)(b * 16 + h) * 2) * 4096 + s;
  size_t i0 = base;
  size_t i1 = base + 4096;
  float s0 = slog[i0], s1 = slog[i1];
  float mx = fmaxf(s0, s1);
  float e0 = __expf(s0 - mx), e1 = __expf(s1 - mx);
  float w0 = e0 / (e0 + e1);
  float w1 = 1.f - w0;
  float v0 = bf2f(ob[i0 * 64 + lane]);
  float v1 = bf2f(ob[i1 * 64 + lane]);
  att[(size_t)bs * 1024 + h * 64 + lane] = f2bf(w0 * v0 + w1 * v1);
}

// ---------------------------------------------------------------------------
extern "C" void kernel_launch(void* const* d_in, const int* in_sizes, int n_in,
                              void* d_out, int out_size, void* d_ws,
                              size_t ws_size, hipStream_t stream) {
  const float* inputs = (const float*)d_in[0];
  const float* ln1s = (const float*)d_in[1];
  const float* ln1b = (const float*)d_in[2];
  const float* wqk = (const float*)d_in[3];
  const float* wv = (const float*)d_in[4];
  const float* wout = (const float*)d_in[5];
  const float* rot = (const float*)d_in[6];
  const float* ln2s = (const float*)d_in[7];
  const float* ln2b = (const float*)d_in[8];
  const float* wm1 = (const float*)d_in[9];
  const float* bm1 = (const float*)d_in[10];
  const float* wm2 = (const float*)d_in[11];
  const float* bm2 = (const float*)d_in[12];

  char* w = (char*)d_ws;
  auto alloc = [&](size_t bytes) {
    char* p = w;
    w += (bytes + 255) & ~(size_t)255;
    return p;
  };
  unsigned short* wqkv_bt = (unsigned short*)alloc(2048ull * 1024 * 2);
  unsigned short* wout_bt = (unsigned short*)alloc(1024ull * 1024 * 2);
  unsigned short* wm1_bt = (unsigned short*)alloc(4096ull * 1024 * 2);
  unsigned short* wm2_bt = (unsigned short*)alloc(1024ull * 4096 * 2);
  unsigned short* bufA = (unsigned short*)alloc(8192ull * 1024 * 2);
  unsigned short* x2b = (unsigned short*)alloc(8192ull * 1024 * 2);
  unsigned short* qb = (unsigned short*)alloc(8192ull * 1024 * 2);
  unsigned short* knb = (unsigned short*)alloc(8192ull * 1024 * 2);
  unsigned short* vb = (unsigned short*)alloc(8192ull * 1024 * 2);
  int* buckets = (int*)alloc(64ull * 4096 * 4);
  int* order = (int*)alloc(64ull * 4096 * 4);
  unsigned short* big =
      (unsigned short*)alloc(8192ull * 4096 * 2);  // obuf then h1
  float* slogb = (float*)alloc(64ull * 4096 * 4);
  unsigned short* obuf = big;
  unsigned short* h1 = big;

  transpose_cast<<<32 * 32, 256, 0, stream>>>(wqk, wqkv_bt, 1024, 1024);
  transpose_cast<<<32 * 32, 256, 0, stream>>>(wv, wqkv_bt + 1024ull * 1024,
                                              1024, 1024);
  transpose_cast<<<32 * 32, 256, 0, stream>>>(wout, wout_bt, 1024, 1024);
  transpose_cast<<<32 * 128, 256, 0, stream>>>(wm1, wm1_bt, 1024, 4096);
  transpose_cast<<<128 * 32, 256, 0, stream>>>(wm2, wm2_bt, 4096, 1024);

  ln_bf16<<<8192, 256, 0, stream>>>(inputs, ln1s, ln1b, bufA);

  // fused qkv projection (8-phase 256²): N=2048 (qk | v), bf16 outputs only
  gemm_8p<5><<<32 * 8, 512, 0, stream>>>(bufA, wqkv_bt, nullptr, qb, vb, 8192,
                                         2048, 1024);

  bucket_kernel<<<4096, 256, 0, stream>>>(qb, rot, knb, buckets);
  sort_kernel<<<64, 256, 0, stream>>>(buckets, order);
  lsh_attn_mfma<<<2048, 256, 0, stream>>>(qb, knb, vb, order, obuf, slogb);
  combine_rounds<<<32768, 256, 0, stream>>>(obuf, slogb, bufA);

  // out-projection + residual -> x2 (bf16)
  gemm_bt<3><<<64 * 8, 256, 0, stream>>>(bufA, wout_bt, nullptr, inputs,
                                         nullptr, nullptr, x2b, 8192, 1024,
                                         1024);
  ln_bf16_b<<<8192, 256, 0, stream>>>(x2b, ln2s, ln2b, bufA);
  // mlp1 (8-phase 256²): bias + gelu -> bf16
  gemm_8p<1><<<32 * 16, 512, 0, stream>>>(bufA, wm1_bt, bm1, h1, nullptr, 8192,
                                          4096, 1024);
  // mlp2 + bias + bf16 residual -> fp32 out
  gemm_bt<4><<<64 * 8, 256, 0, stream>>>(h1, wm2_bt, bm2, nullptr, x2b,
                                         (float*)d_out, nullptr, 8192, 1024,
                                         4096);
}

// Round 21
// 437.105 us; speedup vs baseline: 1.3197x; 1.3197x over previous
//
#include <hip/hip_runtime.h>
#include <hip/hip_bf16.h>

// ---------------------------------------------------------------------------
// ReformerBlockPreLN on MI355X — round 21: revert to r18 (measured best,
// 438 µs). gemm_8p for qkv/mlp1; gemm_bt 2-phase BK=64 for wout/mlp2;
// bf16 x2 residual stream; bf16 qkv; sigmoid-gelu; padded-LDS attention.
// B=2 S=4096 D=1024 H=16 DH=64 R=2 NBUCK=64 CHUNK=128 MLP=4096
// ---------------------------------------------------------------------------

typedef short short8 __attribute__((ext_vector_type(8)));
typedef float f32x4 __attribute__((ext_vector_type(4)));
typedef unsigned short us4 __attribute__((ext_vector_type(4)));

__device__ __forceinline__ unsigned short f2bf(float f) {
  unsigned u = __builtin_bit_cast(unsigned, f);
  u += 0x7FFFu + ((u >> 16) & 1u);
  return (unsigned short)(u >> 16);
}

__device__ __forceinline__ float bf2f(unsigned short u) {
  return __builtin_bit_cast(float, ((unsigned)u) << 16);
}

// gelu tanh-form as sigmoid: 0.5x(1+tanh(u)) == x * sigma(2u)
__device__ __forceinline__ float gelu_f(float x) {
  float y = 1.5957691216057308f * (x + 0.044715f * x * x * x);
  return x / (1.f + __expf(-y));
}

__device__ __forceinline__ void load_lds16(const void* g, void* l) {
  __builtin_amdgcn_global_load_lds(
      (const __attribute__((address_space(1))) unsigned int*)g,
      (__attribute__((address_space(3))) unsigned int*)l, 16, 0, 0);
}

// ---------------------------------------------------------------------------
// transpose + cast fp32 [R][C] -> bf16 [C][R]
// ---------------------------------------------------------------------------
__global__ __launch_bounds__(256) void transpose_cast(
    const float* __restrict__ in, unsigned short* __restrict__ out, int R,
    int C) {
  __shared__ float tile[32][33];
  int ctiles = C >> 5;
  int bx = blockIdx.x % ctiles;
  int by = blockIdx.x / ctiles;
  int tx = threadIdx.x & 31;
  int ty = threadIdx.x >> 5;
#pragma unroll
  for (int i = 0; i < 32; i += 8)
    tile[ty + i][tx] = in[(size_t)(by * 32 + ty + i) * C + bx * 32 + tx];
  __syncthreads();
#pragma unroll
  for (int i = 0; i < 32; i += 8)
    out[(size_t)(bx * 32 + ty + i) * R + by * 32 + tx] = f2bf(tile[tx][ty + i]);
}

// ---------------------------------------------------------------------------
// LayerNorm over D=1024, fp32 in -> bf16 out. One block per row.
// ---------------------------------------------------------------------------
__global__ __launch_bounds__(256) void ln_bf16(const float* __restrict__ x,
                                               const float* __restrict__ sc,
                                               const float* __restrict__ bi,
                                               unsigned short* __restrict__ y) {
  int row = blockIdx.x, tid = threadIdx.x, lane = tid & 63, wv = tid >> 6;
  const float* xr = x + (size_t)row * 1024;
  float4 v = *(const float4*)(xr + tid * 4);
  float s1 = v.x + v.y + v.z + v.w;
  float s2 = v.x * v.x + v.y * v.y + v.z * v.z + v.w * v.w;
#pragma unroll
  for (int o = 1; o < 64; o <<= 1) {
    s1 += __shfl_xor(s1, o);
    s2 += __shfl_xor(s2, o);
  }
  __shared__ float a1[4], a2[4];
  if (lane == 0) {
    a1[wv] = s1;
    a2[wv] = s2;
  }
  __syncthreads();
  s1 = a1[0] + a1[1] + a1[2] + a1[3];
  s2 = a2[0] + a2[1] + a2[2] + a2[3];
  float mu = s1 * (1.f / 1024.f);
  float var = s2 * (1.f / 1024.f) - mu * mu;
  float rs = rsqrtf(var + 1e-6f);
  int c = tid * 4;
  us4 o4;
  o4.x = f2bf((v.x - mu) * rs * sc[c + 0] + bi[c + 0]);
  o4.y = f2bf((v.y - mu) * rs * sc[c + 1] + bi[c + 1]);
  o4.z = f2bf((v.z - mu) * rs * sc[c + 2] + bi[c + 2]);
  o4.w = f2bf((v.w - mu) * rs * sc[c + 3] + bi[c + 3]);
  *(us4*)(y + (size_t)row * 1024 + c) = o4;
}

// ---------------------------------------------------------------------------
// LayerNorm over D=1024, bf16 in -> bf16 out. One block per row.
// ---------------------------------------------------------------------------
__global__ __launch_bounds__(256) void ln_bf16_b(
    const unsigned short* __restrict__ x, const float* __restrict__ sc,
    const float* __restrict__ bi, unsigned short* __restrict__ y) {
  int row = blockIdx.x, tid = threadIdx.x, lane = tid & 63, wv = tid >> 6;
  const unsigned short* xr = x + (size_t)row * 1024;
  us4 vb = *(const us4*)(xr + tid * 4);
  float v0 = bf2f(vb.x), v1 = bf2f(vb.y), v2 = bf2f(vb.z), v3 = bf2f(vb.w);
  float s1 = v0 + v1 + v2 + v3;
  float s2 = v0 * v0 + v1 * v1 + v2 * v2 + v3 * v3;
#pragma unroll
  for (int o = 1; o < 64; o <<= 1) {
    s1 += __shfl_xor(s1, o);
    s2 += __shfl_xor(s2, o);
  }
  __shared__ float a1[4], a2[4];
  if (lane == 0) {
    a1[wv] = s1;
    a2[wv] = s2;
  }
  __syncthreads();
  s1 = a1[0] + a1[1] + a1[2] + a1[3];
  s2 = a2[0] + a2[1] + a2[2] + a2[3];
  float mu = s1 * (1.f / 1024.f);
  float var = s2 * (1.f / 1024.f) - mu * mu;
  float rs = rsqrtf(var + 1e-6f);
  int c = tid * 4;
  us4 o4;
  o4.x = f2bf((v0 - mu) * rs * sc[c + 0] + bi[c + 0]);
  o4.y = f2bf((v1 - mu) * rs * sc[c + 1] + bi[c + 1]);
  o4.z = f2bf((v2 - mu) * rs * sc[c + 2] + bi[c + 2]);
  o4.w = f2bf((v3 - mu) * rs * sc[c + 3] + bi[c + 3]);
  *(us4*)(y + (size_t)row * 1024 + c) = o4;
}

#define PRE_MFMA()                                   \
  __builtin_amdgcn_sched_barrier(0);                 \
  __builtin_amdgcn_s_barrier();                      \
  asm volatile("s_waitcnt lgkmcnt(0)" ::: "memory"); \
  __builtin_amdgcn_sched_barrier(0);                 \
  __builtin_amdgcn_s_setprio(1)
#define POST_MFMA()                  \
  __builtin_amdgcn_s_setprio(0);     \
  __builtin_amdgcn_sched_barrier(0); \
  __builtin_amdgcn_s_barrier()

// ---------------------------------------------------------------------------
// 8-phase 256² 8-wave GEMM (m201 template, r12-proven). BM=BN=256, BK=64,
// 512 threads, 2x4 waves, counted vmcnt(6).
// EPI 1: bias+gelu -> bf16. EPI 5: fused qkv split store (bf16 only).
// ---------------------------------------------------------------------------
template <int EPI>
__global__ __launch_bounds__(512, 2) void gemm_8p(
    const unsigned short* __restrict__ A, const unsigned short* __restrict__ Bt,
    const float* __restrict__ bias, unsigned short* __restrict__ Cb,
    unsigned short* __restrict__ Cb2, int M, int N, int K) {
  __shared__ unsigned short sA[2][256 * 64];
  __shared__ unsigned short sB[2][256 * 64];
  const int nbx = N >> 8;
  const int nwg = gridDim.x;
  const int cpx = nwg >> 3;
  const int bid = blockIdx.x;
  const int swz = (bid & 7) * cpx + (bid >> 3);
  const int bx = swz % nbx;
  const int by = swz / nbx;
  const int tid = threadIdx.x;
  const int lane = tid & 63;
  const int wid = tid >> 6;
  const int wr = wid >> 2;
  const int wc = wid & 3;
  const int l15 = lane & 15;
  const int lhi = lane >> 4;

  const int sr = tid >> 3;  // 0..63
  const int sgl = (tid & 7) ^ (sr & 7);
  const unsigned short* Ab = A + ((size_t)(by * 256) + sr) * K + sgl * 8;
  const unsigned short* Bb = Bt + ((size_t)(bx * 256) + sr) * K + sgl * 8;

  f32x4 acc[8][4];
#pragma unroll
  for (int m = 0; m < 8; ++m)
#pragma unroll
    for (int n = 0; n < 4; ++n) {
      f32x4 z = {0.f, 0.f, 0.f, 0.f};
      acc[m][n] = z;
    }

  const int KT = K >> 6;

  auto ISSUE = [&](int mat, int half, int kt, int buf) {
    const unsigned short* src =
        (mat ? Bb : Ab) + (size_t)(half * 128) * K + kt * 64;
    char* d =
        (char*)(mat ? &sB[buf][0] : &sA[buf][0]) + half * 16384 + tid * 16;
    load_lds16(src, d);
    load_lds16(src + (size_t)64 * K, d + 8192);
  };

  auto rdA = [&](int m, int ks, int c) {
    int row = ((m & 4) << 5) + wr * 64 + ((m & 3) << 4) + l15;
    int pg = ((ks << 2) + lhi) ^ (l15 & 7);
    return *(const short8*)&sA[c][row * 64 + pg * 8];
  };
  auto rdB = [&](int n, int ks, int c) {
    int row = ((n & 2) << 6) + wc * 32 + ((n & 1) << 4) + l15;
    int pg = ((ks << 2) + lhi) ^ (l15 & 7);
    return *(const short8*)&sB[c][row * 64 + pg * 8];
  };

  // prologue
  ISSUE(0, 0, 0, 0);
  ISSUE(1, 0, 0, 0);
  ISSUE(0, 1, 0, 0);
  ISSUE(1, 1, 0, 0);
  asm volatile("s_waitcnt vmcnt(4)" ::: "memory");
  if (KT > 1) {
    ISSUE(0, 0, 1, 1);
    ISSUE(1, 0, 1, 1);
    ISSUE(0, 1, 1, 1);
  }
  asm volatile("s_waitcnt vmcnt(6)" ::: "memory");
  __builtin_amdgcn_sched_barrier(0);
  __builtin_amdgcn_s_barrier();

  for (int kt = 0; kt < KT; ++kt) {
    const int c = kt & 1;
    short8 a0[4][2], a1[4][2], b0[2][2], b1[2][2];

    // phase 0: (m0-3, n0-1); issue Bh1(kt+1) -> buf c^1
#pragma unroll
    for (int m = 0; m < 4; ++m)
#pragma unroll
      for (int ks = 0; ks < 2; ++ks) a0[m][ks] = rdA(m, ks, c);
#pragma unroll
    for (int n = 0; n < 2; ++n)
#pragma unroll
      for (int ks = 0; ks < 2; ++ks) b0[n][ks] = rdB(n, ks, c);
    if (kt + 1 < KT) ISSUE(1, 1, kt + 1, c ^ 1);
    PRE_MFMA();
#pragma unroll
    for (int m = 0; m < 4; ++m)
#pragma unroll
      for (int n = 0; n < 2; ++n)
#pragma unroll
        for (int ks = 0; ks < 2; ++ks)
          acc[m][n] = __builtin_amdgcn_mfma_f32_16x16x32_bf16(
              a0[m][ks], b0[n][ks], acc[m][n], 0, 0, 0);
    POST_MFMA();

    // phase 1: (m4-7, n0-1); issue Ah0(kt+2) -> buf c
#pragma unroll
    for (int m = 0; m < 4; ++m)
#pragma unroll
      for (int ks = 0; ks < 2; ++ks) a1[m][ks] = rdA(4 + m, ks, c);
    if (kt + 2 < KT) ISSUE(0, 0, kt + 2, c);
    PRE_MFMA();
#pragma unroll
    for (int m = 0; m < 4; ++m)
#pragma unroll
      for (int n = 0; n < 2; ++n)
#pragma unroll
        for (int ks = 0; ks < 2; ++ks)
          acc[4 + m][n] = __builtin_amdgcn_mfma_f32_16x16x32_bf16(
              a1[m][ks], b0[n][ks], acc[4 + m][n], 0, 0, 0);
    POST_MFMA();

    // phase 2: (m4-7, n2-3); issue Bh0(kt+2) -> buf c
#pragma unroll
    for (int n = 0; n < 2; ++n)
#pragma unroll
      for (int ks = 0; ks < 2; ++ks) b1[n][ks] = rdB(2 + n, ks, c);
    if (kt + 2 < KT) ISSUE(1, 0, kt + 2, c);
    PRE_MFMA();
#pragma unroll
    for (int m = 0; m < 4; ++m)
#pragma unroll
      for (int n = 0; n < 2; ++n)
#pragma unroll
        for (int ks = 0; ks < 2; ++ks)
          acc[4 + m][2 + n] = __builtin_amdgcn_mfma_f32_16x16x32_bf16(
              a1[m][ks], b1[n][ks], acc[4 + m][2 + n], 0, 0, 0);
    POST_MFMA();

    // phase 3: (m0-3, n2-3), no reads; issue Ah1(kt+2) -> buf c
    if (kt + 2 < KT) ISSUE(0, 1, kt + 2, c);
    __builtin_amdgcn_s_setprio(1);
#pragma unroll
    for (int m = 0; m < 4; ++m)
#pragma unroll
      for (int n = 0; n < 2; ++n)
#pragma unroll
        for (int ks = 0; ks < 2; ++ks)
          acc[m][2 + n] = __builtin_amdgcn_mfma_f32_16x16x32_bf16(
              a0[m][ks], b1[n][ks], acc[m][2 + n], 0, 0, 0);
    __builtin_amdgcn_s_setprio(0);
    if (kt + 1 < KT) {
      if (kt + 2 < KT) {
        asm volatile("s_waitcnt vmcnt(6)" ::: "memory");
      } else {
        asm volatile("s_waitcnt vmcnt(0)" ::: "memory");
      }
      __builtin_amdgcn_sched_barrier(0);
      __builtin_amdgcn_s_barrier();
    }
  }

  const int r0 = by * 256 + wr * 64;
  const int c0 = bx * 256 + wc * 32;
#pragma unroll
  for (int m = 0; m < 8; ++m) {
    const int rb = r0 + ((m & 4) << 5) + ((m & 3) << 4) + lhi * 4;
#pragma unroll
    for (int n = 0; n < 4; ++n) {
      const int cc = c0 + ((n & 2) << 6) + ((n & 1) << 4) + l15;
#pragma unroll
      for (int i = 0; i < 4; ++i) {
        const int rr = rb + i;
        float vacc = acc[m][n][i];
        if (EPI == 1) {
          Cb[(size_t)rr * N + cc] = f2bf(gelu_f(vacc + bias[cc]));
        } else if (EPI == 5) {
          if (cc < 1024) {
            Cb[(size_t)rr * 1024 + cc] = f2bf(vacc);
          } else {
            Cb2[(size_t)rr * 1024 + (cc - 1024)] = f2bf(vacc);
          }
        }
      }
    }
  }
}

#undef PRE_MFMA
#undef POST_MFMA

// ---------------------------------------------------------------------------
// 2-phase bf16 GEMM (r12-proven), 128x128 tile, BK=64, grid 512 = 2
// blocks/CU. Used for wout, mlp2.
// EPI 3: acc + fp32 res -> bf16 (wout -> x2b).
// EPI 4: acc + bias + bf16 res -> fp32 (mlp2 -> d_out).
// ---------------------------------------------------------------------------
template <int EPI>
__global__ __launch_bounds__(256) void gemm_bt(
    const unsigned short* __restrict__ A, const unsigned short* __restrict__ Bt,
    const float* __restrict__ bias, const float* __restrict__ res,
    const unsigned short* __restrict__ resb, float* __restrict__ Cf,
    unsigned short* __restrict__ Cb, int M, int N, int K) {
  __shared__ unsigned short sA[2][128 * 64];
  __shared__ unsigned short sB[2][128 * 64];
  const int nbx = N / 128;
  const int nwg = gridDim.x;
  const int cpx = nwg >> 3;
  const int bid = blockIdx.x;
  const int swz = (bid & 7) * cpx + (bid >> 3);
  const int bx = swz % nbx;
  const int by = swz / nbx;
  const int tid = threadIdx.x;
  const int lane = tid & 63;
  const int wave = tid >> 6;
  const int wr = wave >> 1, wc = wave & 1;
  const int l15 = lane & 15;
  const int lhi = lane >> 4;

  const int srow = tid >> 3;  // 0..31
  const int sgl = (tid & 7) ^ (srow & 7);
  const unsigned short* Ag = A + (size_t)(by * 128 + srow) * K + sgl * 8;
  const unsigned short* Bg = Bt + (size_t)(bx * 128 + srow) * K + sgl * 8;

  f32x4 acc[4][4];
#pragma unroll
  for (int m = 0; m < 4; ++m)
#pragma unroll
    for (int n = 0; n < 4; ++n) {
      f32x4 z = {0.f, 0.f, 0.f, 0.f};
      acc[m][n] = z;
    }

  const int KT = K / 64;

  auto STAGE = [&](int ktile, int buf) {
    const unsigned short* As = Ag + (size_t)ktile * 64;
    const unsigned short* Bs = Bg + (size_t)ktile * 64;
#pragma unroll
    for (int i = 0; i < 4; ++i) {
      load_lds16(As + (size_t)i * 32 * K,
                 (char*)&sA[buf][0] + tid * 16 + i * 4096);
      load_lds16(Bs + (size_t)i * 32 * K,
                 (char*)&sB[buf][0] + tid * 16 + i * 4096);
    }
  };

  STAGE(0, 0);
  __syncthreads();

  int cur = 0;
  const int arow = wr * 64 + l15;
  const int brow = wc * 64 + l15;

  for (int kt = 0; kt < KT; ++kt) {
    if (kt + 1 < KT) STAGE(kt + 1, cur ^ 1);
#pragma unroll
    for (int ks = 0; ks < 2; ++ks) {
      const int koff = (((ks * 4 + lhi) ^ (l15 & 7)) << 3);
      short8 af[4], bfv[4];
#pragma unroll
      for (int m = 0; m < 4; ++m)
        af[m] = *(const short8*)&sA[cur][(arow + m * 16) * 64 + koff];
#pragma unroll
      for (int n = 0; n < 4; ++n)
        bfv[n] = *(const short8*)&sB[cur][(brow + n * 16) * 64 + koff];
#pragma unroll
      for (int m = 0; m < 4; ++m)
#pragma unroll
        for (int n = 0; n < 4; ++n)
          acc[m][n] = __builtin_amdgcn_mfma_f32_16x16x32_bf16(
              af[m], bfv[n], acc[m][n], 0, 0, 0);
    }
    __syncthreads();
    cur ^= 1;
  }

  const int r0 = by * 128 + wr * 64;
  const int c0 = bx * 128 + wc * 64;
#pragma unroll
  for (int m = 0; m < 4; ++m) {
#pragma unroll
    for (int n = 0; n < 4; ++n) {
#pragma unroll
      for (int i = 0; i < 4; ++i) {
        int rr = r0 + m * 16 + lhi * 4 + i;
        int cc = c0 + n * 16 + l15;
        float vacc = acc[m][n][i];
        if (EPI == 3) {
          float t = vacc + res[(size_t)rr * N + cc];
          Cb[(size_t)rr * N + cc] = f2bf(t);
        } else if (EPI == 4) {
          float t = vacc + bias[cc] + bf2f(resb[(size_t)rr * N + cc]);
          Cf[(size_t)rr * N + cc] = t;
        }
      }
    }
  }
}

// ---------------------------------------------------------------------------
// Buckets + normalized-K pack. One wave per (b,h,s) token. bf16 qk input.
// ---------------------------------------------------------------------------
__global__ __launch_bounds__(256) void bucket_kernel(
    const unsigned short* __restrict__ qk, const float* __restrict__ rot,
    unsigned short* __restrict__ knb, int* __restrict__ buckets) {
  __shared__ float rotl[64 * 64];
  __shared__ float xnl[4][64];
  int tid = threadIdx.x, lane = tid & 63, wv = tid >> 6;
  for (int i = tid; i < 4096; i += 256) rotl[i] = rot[i];
  __syncthreads();
  for (int it = 0; it < 8; ++it) {
    int g = (it * 4096 + blockIdx.x) * 4 + wv;
    int bh = g >> 12;
    int s = g & 4095;
    int b = bh >> 4, h = bh & 15;
    size_t rowoff = (size_t)(b * 4096 + s) * 1024 + h * 64;
    float x = bf2f(qk[rowoff + lane]);
    float ss = x * x;
#pragma unroll
    for (int o = 1; o < 64; o <<= 1) ss += __shfl_xor(ss, o);
    float rn = 1.f / (sqrtf(ss) + 1e-6f);
    float xn = x * rn;
    knb[rowoff + lane] = f2bf(xn);
    xnl[wv][lane] = xn;
    __syncthreads();
    int r_ = lane >> 5, m_ = lane & 31;
    float a = 0.f;
#pragma unroll 16
    for (int d = 0; d < 64; ++d) a += xnl[wv][d] * rotl[d * 64 + r_ * 32 + m_];
    float bv;
    int bi;
    if (a >= 0.f) {
      bv = a;
      bi = m_;
    } else {
      bv = -a;
      bi = m_ + 32;
    }
#pragma unroll
    for (int o = 16; o >= 1; o >>= 1) {
      float ov = __shfl_xor(bv, o);
      int oi = __shfl_xor(bi, o);
      if (ov > bv || (ov == bv && oi < bi)) {
        bv = ov;
        bi = oi;
      }
    }
    if (m_ == 0) buckets[((size_t)bh * 2 + r_) * 4096 + s] = bi;
    __syncthreads();
  }
}

// ---------------------------------------------------------------------------
// Parallel stable counting sort. One block (256 threads) per (b,h,r).
// ---------------------------------------------------------------------------
#define HSTR 65

__global__ __launch_bounds__(256) void sort_kernel(
    const int* __restrict__ buckets, int* __restrict__ order) {
  __shared__ unsigned int hist[256 * HSTR];
  __shared__ unsigned int bucketStart[64];
  const int bhr = blockIdx.x;
  const int t = threadIdx.x;
  const int* bk = buckets + (size_t)bhr * 4096;

  unsigned int* hrow = &hist[t * HSTR];
#pragma unroll
  for (int b = 0; b < 64; ++b) hrow[b] = 0u;

  int bks[16];
  {
    const int4* bp = (const int4*)(bk + t * 16);
#pragma unroll
    for (int j4 = 0; j4 < 4; ++j4) {
      int4 v = bp[j4];
      bks[j4 * 4 + 0] = v.x;
      bks[j4 * 4 + 1] = v.y;
      bks[j4 * 4 + 2] = v.z;
      bks[j4 * 4 + 3] = v.w;
    }
  }
#pragma unroll
  for (int j = 0; j < 16; ++j) hrow[bks[j]]++;
  __syncthreads();

  if (t < 64) {
    unsigned int acc = 0;
    for (int t2 = 0; t2 < 256; ++t2) {
      unsigned int c = hist[t2 * HSTR + t];
      hist[t2 * HSTR + t] = acc;
      acc += c;
    }
    bucketStart[t] = acc;
  }
  __syncthreads();
  if (t == 0) {
    unsigned int acc = 0;
    for (int b = 0; b < 64; ++b) {
      unsigned int c = bucketStart[b];
      bucketStart[b] = acc;
      acc += c;
    }
  }
  __syncthreads();

  int* op = order + (size_t)bhr * 4096;
#pragma unroll
  for (int j = 0; j < 16; ++j) {
    int b = bks[j];
    unsigned int pos = bucketStart[b] + hrow[b];
    hrow[b]++;
    op[pos] = t * 16 + j;
  }
}

// ---------------------------------------------------------------------------
// MFMA LSH attention, all-bf16 data path. One block per (b,h,r,chunk).
// ---------------------------------------------------------------------------
#define KSTR 72
#define PSTR 136

__global__ __launch_bounds__(256, 2) void lsh_attn_mfma(
    const unsigned short* __restrict__ qb, const unsigned short* __restrict__ knb,
    const unsigned short* __restrict__ vb, const int* __restrict__ order,
    unsigned short* __restrict__ ob, float* __restrict__ slog) {
  __shared__ unsigned short Kls[128 * KSTR];
  __shared__ unsigned short Vt[64 * PSTR];
  __shared__ unsigned short Pls[4][32 * PSTR];
  __shared__ int qtokL[128];
  __shared__ int btok[128];

  const int bid = blockIdx.x;                   // grid = 2048
  const int swz = (bid & 7) * 256 + (bid >> 3); // chunked XCD swizzle
  const int c = swz & 31;
  const int bhr = swz >> 5;
  const int bh = bhr >> 1;
  const int h = bh & 15, b = bh >> 4;
  const int* ord = order + (size_t)bhr * 4096;
  const int tid = threadIdx.x, lane = tid & 63, wv = tid >> 6;
  const int l15 = lane & 15, lhi = lane >> 4;

  if (tid < 128) qtokL[tid] = ord[c * 128 + tid];
  __syncthreads();

  short8 qf[2][2];
#pragma unroll
  for (int mt = 0; mt < 2; ++mt) {
#pragma unroll
    for (int ks = 0; ks < 2; ++ks) {
      int tok = qtokL[wv * 32 + mt * 16 + l15];
      qf[mt][ks] = *(const short8*)(qb + (size_t)(b * 4096 + tok) * 1024 +
                                    h * 64 + ks * 32 + lhi * 8);
    }
  }

  float mrun[2][4], lrun[2][4];
  f32x4 oacc[2][4];
#pragma unroll
  for (int mt = 0; mt < 2; ++mt)
#pragma unroll
    for (int i = 0; i < 4; ++i) {
      mrun[mt][i] = -1e30f;
      lrun[mt][i] = 0.f;
    }
#pragma unroll
  for (int mt = 0; mt < 2; ++mt)
#pragma unroll
    for (int n = 0; n < 4; ++n) {
      f32x4 z = {0.f, 0.f, 0.f, 0.f};
      oacc[mt][n] = z;
    }

  for (int st = 0; st < 3; ++st) {
    int kc = (st == 0) ? c : (st == 1) ? ((c + 31) & 31) : ((c + 1) & 31);
    __syncthreads();
    {
      int row = tid >> 1, half = tid & 1;
      int ktok = ord[kc * 128 + row];
      if (half == 0) btok[row] = ktok;
      size_t rowoff = (size_t)(b * 4096 + ktok) * 1024 + h * 64 + half * 32;
      const short8* kp = (const short8*)(knb + rowoff);
      const short8* vp = (const short8*)(vb + rowoff);
#pragma unroll
      for (int i = 0; i < 4; ++i)
        *(short8*)&Kls[row * KSTR + half * 32 + i * 8] = kp[i];
#pragma unroll
      for (int i = 0; i < 4; ++i) {
        short8 vw = vp[i];
        int d0 = half * 32 + i * 8;
#pragma unroll
        for (int j = 0; j < 8; ++j)
          Vt[(d0 + j) * PSTR + row] = (unsigned short)vw[j];
      }
    }
    __syncthreads();

    f32x4 sacc[2][8];
#pragma unroll
    for (int mt = 0; mt < 2; ++mt)
#pragma unroll
      for (int n = 0; n < 8; ++n) {
        f32x4 z = {0.f, 0.f, 0.f, 0.f};
        sacc[mt][n] = z;
      }
#pragma unroll
    for (int ks = 0; ks < 2; ++ks) {
      short8 kf[8];
#pragma unroll
      for (int n = 0; n < 8; ++n)
        kf[n] = *(const short8*)&Kls[(n * 16 + l15) * KSTR + ks * 32 + lhi * 8];
#pragma unroll
      for (int mt = 0; mt < 2; ++mt)
#pragma unroll
        for (int n = 0; n < 8; ++n)
          sacc[mt][n] = __builtin_amdgcn_mfma_f32_16x16x32_bf16(
              qf[mt][ks], kf[n], sacc[mt][n], 0, 0, 0);
    }

    int ktA[8];
#pragma unroll
    for (int n = 0; n < 8; ++n) ktA[n] = btok[n * 16 + l15];
#pragma unroll
    for (int mt = 0; mt < 2; ++mt) {
#pragma unroll
      for (int i = 0; i < 4; ++i) {
        int qrow = wv * 32 + mt * 16 + lhi * 4 + i;
        int qt = qtokL[qrow];
        float sv[8];
        float mx = -1e30f;
#pragma unroll
        for (int n = 0; n < 8; ++n) {
          float s = sacc[mt][n][i] * 0.125f;
          if (ktA[n] == qt) s -= 1e5f;
          sv[n] = s;
          mx = fmaxf(mx, s);
        }
#pragma unroll
        for (int d = 1; d < 16; d <<= 1) mx = fmaxf(mx, __shfl_xor(mx, d));
        float mold = mrun[mt][i];
        float mnew = fmaxf(mold, mx);
        float scl = __expf(mold - mnew);
        lrun[mt][i] *= scl;
#pragma unroll
        for (int n = 0; n < 4; ++n) oacc[mt][n][i] *= scl;
        float ps = 0.f;
#pragma unroll
        for (int n = 0; n < 8; ++n) {
          float p = __expf(sv[n] - mnew);
          ps += p;
          Pls[wv][(mt * 16 + lhi * 4 + i) * PSTR + n * 16 + l15] = f2bf(p);
        }
#pragma unroll
        for (int d = 1; d < 16; d <<= 1) ps += __shfl_xor(ps, d);
        lrun[mt][i] = lrun[mt][i] + ps;
        mrun[mt][i] = mnew;
      }
    }

#pragma unroll
    for (int ks = 0; ks < 4; ++ks) {
      short8 pf[2];
#pragma unroll
      for (int mt = 0; mt < 2; ++mt)
        pf[mt] =
            *(const short8*)&Pls[wv][(mt * 16 + l15) * PSTR + ks * 32 + lhi * 8];
      short8 vfr[4];
#pragma unroll
      for (int n = 0; n < 4; ++n)
        vfr[n] = *(const short8*)&Vt[(n * 16 + l15) * PSTR + ks * 32 + lhi * 8];
#pragma unroll
      for (int mt = 0; mt < 2; ++mt)
#pragma unroll
        for (int n = 0; n < 4; ++n)
          oacc[mt][n] = __builtin_amdgcn_mfma_f32_16x16x32_bf16(
              pf[mt], vfr[n], oacc[mt][n], 0, 0, 0);
    }
  }

#pragma unroll
  for (int mt = 0; mt < 2; ++mt) {
#pragma unroll
    for (int i = 0; i < 4; ++i) {
      int qrow = wv * 32 + mt * 16 + lhi * 4 + i;
      int tok = qtokL[qrow];
      float l = lrun[mt][i];
      float invl = 1.f / l;
      if (l15 == 0) slog[(size_t)bhr * 4096 + tok] = logf(l) + mrun[mt][i];
      unsigned short* orow = ob + ((size_t)bhr * 4096 + tok) * 64;
#pragma unroll
      for (int n = 0; n < 4; ++n)
        orow[n * 16 + l15] = f2bf(oacc[mt][n][i] * invl);
    }
  }
}

// ---------------------------------------------------------------------------
// Combine hash rounds: w = softmax over r of slog; att = sum_r w_r * o_r.
// ---------------------------------------------------------------------------
__global__ __launch_bounds__(256) void combine_rounds(
    const unsigned short* __restrict__ ob, const float* __restrict__ slog,
    unsigned short* __restrict__ att) {
  int g = blockIdx.x * 4 + (threadIdx.x >> 6);
  int lane = threadIdx.x & 63;
  int h = g & 15;
  int bs = g >> 4;
  int b = bs >> 12;
  int s = bs & 4095;
  size_t base = ((size_t)(b * 16 + h) * 2) * 4096 + s;
  size_t i0 = base;
  size_t i1 = base + 4096;
  float s0 = slog[i0], s1 = slog[i1];
  float mx = fmaxf(s0, s1);
  float e0 = __expf(s0 - mx), e1 = __expf(s1 - mx);
  float w0 = e0 / (e0 + e1);
  float w1 = 1.f - w0;
  float v0 = bf2f(ob[i0 * 64 + lane]);
  float v1 = bf2f(ob[i1 * 64 + lane]);
  att[(size_t)bs * 1024 + h * 64 + lane] = f2bf(w0 * v0 + w1 * v1);
}

// ---------------------------------------------------------------------------
extern "C" void kernel_launch(void* const* d_in, const int* in_sizes, int n_in,
                              void* d_out, int out_size, void* d_ws,
                              size_t ws_size, hipStream_t stream) {
  const float* inputs = (const float*)d_in[0];
  const float* ln1s = (const float*)d_in[1];
  const float* ln1b = (const float*)d_in[2];
  const float* wqk = (const float*)d_in[3];
  const float* wv = (const float*)d_in[4];
  const float* wout = (const float*)d_in[5];
  const float* rot = (const float*)d_in[6];
  const float* ln2s = (const float*)d_in[7];
  const float* ln2b = (const float*)d_in[8];
  const float* wm1 = (const float*)d_in[9];
  const float* bm1 = (const float*)d_in[10];
  const float* wm2 = (const float*)d_in[11];
  const float* bm2 = (const float*)d_in[12];

  char* w = (char*)d_ws;
  auto alloc = [&](size_t bytes) {
    char* p = w;
    w += (bytes + 255) & ~(size_t)255;
    return p;
  };
  unsigned short* wqkv_bt = (unsigned short*)alloc(2048ull * 1024 * 2);
  unsigned short* wout_bt = (unsigned short*)alloc(1024ull * 1024 * 2);
  unsigned short* wm1_bt = (unsigned short*)alloc(4096ull * 1024 * 2);
  unsigned short* wm2_bt = (unsigned short*)alloc(1024ull * 4096 * 2);
  unsigned short* bufA = (unsigned short*)alloc(8192ull * 1024 * 2);
  unsigned short* x2b = (unsigned short*)alloc(8192ull * 1024 * 2);
  unsigned short* qb = (unsigned short*)alloc(8192ull * 1024 * 2);
  unsigned short* knb = (unsigned short*)alloc(8192ull * 1024 * 2);
  unsigned short* vb = (unsigned short*)alloc(8192ull * 1024 * 2);
  int* buckets = (int*)alloc(64ull * 4096 * 4);
  int* order = (int*)alloc(64ull * 4096 * 4);
  unsigned short* big =
      (unsigned short*)alloc(8192ull * 4096 * 2);  // obuf then h1
  float* slogb = (float*)alloc(64ull * 4096 * 4);
  unsigned short* obuf = big;
  unsigned short* h1 = big;

  transpose_cast<<<32 * 32, 256, 0, stream>>>(wqk, wqkv_bt, 1024, 1024);
  transpose_cast<<<32 * 32, 256, 0, stream>>>(wv, wqkv_bt + 1024ull * 1024,
                                              1024, 1024);
  transpose_cast<<<32 * 32, 256, 0, stream>>>(wout, wout_bt, 1024, 1024);
  transpose_cast<<<32 * 128, 256, 0, stream>>>(wm1, wm1_bt, 1024, 4096);
  transpose_cast<<<128 * 32, 256, 0, stream>>>(wm2, wm2_bt, 4096, 1024);

  ln_bf16<<<8192, 256, 0, stream>>>(inputs, ln1s, ln1b, bufA);

  // fused qkv projection (8-phase 256²): N=2048 (qk | v), bf16 outputs only
  gemm_8p<5><<<32 * 8, 512, 0, stream>>>(bufA, wqkv_bt, nullptr, qb, vb, 8192,
                                         2048, 1024);

  bucket_kernel<<<4096, 256, 0, stream>>>(qb, rot, knb, buckets);
  sort_kernel<<<64, 256, 0, stream>>>(buckets, order);
  lsh_attn_mfma<<<2048, 256, 0, stream>>>(qb, knb, vb, order, obuf, slogb);
  combine_rounds<<<32768, 256, 0, stream>>>(obuf, slogb, bufA);

  // out-projection + residual -> x2 (bf16)
  gemm_bt<3><<<64 * 8, 256, 0, stream>>>(bufA, wout_bt, nullptr, inputs,
                                         nullptr, nullptr, x2b, 8192, 1024,
                                         1024);
  ln_bf16_b<<<8192, 256, 0, stream>>>(x2b, ln2s, ln2b, bufA);
  // mlp1 (8-phase 256²): bias + gelu -> bf16
  gemm_8p<1><<<32 * 16, 512, 0, stream>>>(bufA, wm1_bt, bm1, h1, nullptr, 8192,
                                          4096, 1024);
  // mlp2 + bias + bf16 residual -> fp32 out
  gemm_bt<4><<<64 * 8, 256, 0, stream>>>(h1, wm2_bt, bm2, nullptr, x2b,
                                         (float*)d_out, nullptr, 8192, 1024,
                                         4096);
}